// Round 12
// baseline (454.340 us; speedup 1.0000x reference)
//
#include <hip/hip_runtime.h>
#include <hip/hip_cooperative_groups.h>
#include <math.h>

namespace cg = cooperative_groups;

#define N_NODES 20000
#define NP1     20001   // +1 sentinel slot (rank 20000: zero row, -inf logit)
#define IN_CH   512
#define HID_TOT 512   // 8 heads * 64
#define OUT_CH  256
#define N_EDGE  320000
#define TOT_EDGE (N_EDGE + N_NODES)  // 340000 incl self-loops
#define EPAD    400000               // max padded edges: 340000 + 3*20000
#define NSEG    ((N_NODES + 255) / 256)   // 79 segments of 256 nodes
#define CSR_BLOCKS 512

typedef __attribute__((ext_vector_type(8))) short short8;
typedef __attribute__((ext_vector_type(4))) float f32x4;
typedef __attribute__((ext_vector_type(2))) float f32x2;

__device__ __forceinline__ ushort f2bf(float f) {
    union { float f; unsigned u; } v; v.f = f;
    unsigned u = v.u;
    return (ushort)((u + 0x7fffu + ((u >> 16) & 1u)) >> 16);  // RNE
}

// async global->LDS, 16B per lane (m97 pattern; dest = wave-uniform base + lane*16)
__device__ __forceinline__ void glds16(const ushort* g, ushort* l) {
    __builtin_amdgcn_global_load_lds(
        (const __attribute__((address_space(1))) void*)g,
        (__attribute__((address_space(3))) void*)l, 16, 0, 0);
}

// leaky_relu(a, 0.2) == max(a, 0.2a) for all a (single VALU op)
__device__ __forceinline__ float lrelu(float a) { return fmaxf(a, 0.2f * a); }

// ------- fused prep: cast x, transpose-cast W1/W2, zero/sentinel init ------
#define NA_BLK (N_NODES * IN_CH / 4 / 256)          // 10000
#define NB_BLK ((IN_CH / 64) * (HID_TOT / 4))       // 1024
#define NC_BLK ((HID_TOT / 64) * (OUT_CH / 4))      // 512
#define NZ_BLK ((N_NODES + 255) / 256)              // 79
__global__ __launch_bounds__(256) void prep_kernel(const float* __restrict__ x,
                                                   ushort* __restrict__ xb,
                                                   const float* __restrict__ W1,
                                                   ushort* __restrict__ w1t,
                                                   const float* __restrict__ W2,
                                                   ushort* __restrict__ w2t,
                                                   int* __restrict__ counts,
                                                   float* __restrict__ as1,
                                                   float* __restrict__ as2,
                                                   float* __restrict__ ad2,
                                                   unsigned char* __restrict__ h1f,
                                                   unsigned char* __restrict__ h2f) {
    int b = blockIdx.x;
    int t = threadIdx.x;
    if (b < NA_BLK) {
        int i = b * 256 + t;
        float4 v = *(const float4*)&x[(size_t)i * 4];
        ushort4 o = make_ushort4(f2bf(v.x), f2bf(v.y), f2bf(v.z), f2bf(v.w));
        *(ushort4*)&xb[(size_t)i * 4] = o;
    } else if (b < NA_BLK + NB_BLK) {
        int bb = b - NA_BLK;
        int k = (bb & 7) * 64 + (t & 63);
        int n = (bb >> 3) * 4 + (t >> 6);
        w1t[(size_t)n * IN_CH + k] = f2bf(W1[(size_t)k * HID_TOT + n]);
    } else if (b < NA_BLK + NB_BLK + NC_BLK) {
        int bb = b - NA_BLK - NB_BLK;
        int k = (bb & 7) * 64 + (t & 63);
        int n = (bb >> 3) * 4 + (t >> 6);
        w2t[(size_t)n * HID_TOT + k] = f2bf(W2[(size_t)k * OUT_CH + n]);
    } else {
        int i = (b - NA_BLK - NB_BLK - NC_BLK) * 256 + t;
        if (i < N_NODES) { counts[i] = 0; as2[i] = 0.f; ad2[i] = 0.f; }
        if (i == N_NODES) as2[N_NODES] = -1e30f;            // sentinel logit L2
        if (i < 8) as1[(size_t)i * NP1 + N_NODES] = -1e30f; // sentinel logits L1
        // zero sentinel rows: h1f head-major (8 heads x 64B), h2f (256B)
        if (i < 128)
            ((unsigned*)(h1f + ((size_t)(i >> 4) * NP1 + N_NODES) * 64))[i & 15] = 0u;
        if (i < 64)
            ((unsigned*)(h2f + (size_t)N_NODES * OUT_CH))[i] = 0u;
    }
}

// ---- fused CSR build (cooperative): hist + segment-sort + 2-level scan +
// scatter in ONE kernel with grid.sync() — replaces 4 kernels + 3 launch
// gaps (incl. a 1-block scan that idled 255 CUs). 512 blocks co-resident.
__global__ __launch_bounds__(256) void csr_kernel(const int* __restrict__ ei,
                                                  int* __restrict__ counts,
                                                  int* __restrict__ perm,
                                                  int* __restrict__ invperm,
                                                  int* __restrict__ pcnt,
                                                  int* __restrict__ segpre,
                                                  int* __restrict__ offsets,
                                                  int* __restrict__ cursors,
                                                  ushort* __restrict__ srcs) {
    cg::grid_group grid = cg::this_grid();
    int t = threadIdx.x;
    int gtid = blockIdx.x * 256 + t;
    int gstride = gridDim.x * 256;
    __shared__ int bins[64], starts[64], redsum[4], wsum[4], woff[4];

    // phase 1: degree histogram over edges (+self-loops)
    for (int e = gtid; e < TOT_EDGE; e += gstride) {
        int d = (e < N_EDGE) ? ei[N_EDGE + e] : (e - N_EDGE);
        atomicAdd(&counts[d], 1);
    }
    grid.sync();

    // phase 2: segment-local degree sort (perm/invperm/pcnt) + padded seg sum
    for (int seg = blockIdx.x; seg < NSEG; seg += gridDim.x) {
        int v = seg * 256 + t;
        bool valid = (v < N_NODES);
        if (t < 64) bins[t] = 0;
        __syncthreads();
        int dreal = 0, d = 0, rank = 0;
        if (valid) {
            dreal = counts[v];
            d = dreal; if (d > 63) d = 63;
            rank = atomicAdd(&bins[d], 1);
        }
        __syncthreads();
        if (t == 0) {
            int r = 0;
            for (int k = 0; k < 64; k++) { starts[k] = r; r += bins[k]; }
        }
        __syncthreads();
        if (valid) {
            int pos = seg * 256 + starts[d] + rank;
            perm[pos] = v;
            invperm[v] = pos;
            pcnt[pos] = dreal;
        }
        int pad = valid ? ((dreal + 3) & ~3) : 0;
#pragma unroll
        for (int off = 1; off < 64; off <<= 1) pad += __shfl_xor(pad, off);
        if ((t & 63) == 0) redsum[t >> 6] = pad;
        __syncthreads();
        if (t == 0) segpre[seg] = redsum[0] + redsum[1] + redsum[2] + redsum[3];
        __syncthreads();
    }
    grid.sync();

    // phase 3: exclusive scan of NSEG segment sums (trivial serial)
    if (blockIdx.x == 0 && t == 0) {
        int r = 0;
        for (int s2 = 0; s2 < NSEG; s2++) { int c = segpre[s2]; segpre[s2] = r; r += c; }
        offsets[N_NODES] = r;
    }
    grid.sync();

    // phase 4: per-segment offsets = segbase + local excl prefix of padded pcnt
    for (int seg = blockIdx.x; seg < NSEG; seg += gridDim.x) {
        int idx = seg * 256 + t;
        int cnt = (idx < N_NODES) ? pcnt[idx] : 0;
        int pad = (cnt + 3) & ~3;
        int lane = t & 63, wid = t >> 6;
        int val = pad;
#pragma unroll
        for (int off = 1; off < 64; off <<= 1) {
            int y = __shfl_up(val, off);
            if (lane >= off) val += y;
        }
        if (lane == 63) wsum[wid] = val;
        __syncthreads();
        if (t == 0) {
            int r = 0;
            for (int w = 0; w < 4; w++) { woff[w] = r; r += wsum[w]; }
        }
        __syncthreads();
        int excl = segpre[seg] + woff[wid] + (val - pad);
        if (idx < N_NODES) { offsets[idx] = excl; cursors[idx] = excl; }
        __syncthreads();
    }
    grid.sync();

    // phase 5: scatter (ushort ranks) + pad-fill (disjoint ranges, concurrent)
    for (int e = gtid; e < TOT_EDGE; e += gstride) {
        int s, d;
        if (e < N_EDGE) { s = ei[e]; d = ei[N_EDGE + e]; } else { s = e - N_EDGE; d = s; }
        int dr = invperm[d];
        int pos = atomicAdd(&cursors[dr], 1);
        srcs[pos] = (ushort)invperm[s];
    }
    for (int rk = gtid; rk < N_NODES; rk += gstride) {
        int o = offsets[rk] + pcnt[rk], e2 = offsets[rk + 1];
        for (int pp = o; pp < e2; pp++) srcs[pp] = (ushort)N_NODES;
    }
}

// --- bf16 MFMA GEMM + fused attention-logit epilogue, fp8 h output --------
// BM=128, BN=128, BK=64. 4 waves in 2x2; wave tile 64x64.
// 1D grid + XCD-chunked bijective swizzle (m204): consecutive chunk entries
// on one XCD share a row-panel -> A panel fetched from HBM once per XCD.
// aHM: A is head-major rank-space [8][NP1][64] bf16 (BK=64 == one head per
//      k-step -> pointer advance is k0*NP1 instead of k0).
// layer1: wave's 64 cols == one head; C (fp8) + logits scattered to
//         invperm[rg] in head-major rank space -> downstream is all linear.
// layer2: C rows are ranks already; 4 atomicAdd logit partials.
__global__ __launch_bounds__(256, 2) void gemm_mfma_kernel(const ushort* __restrict__ A,
                                                           const ushort* __restrict__ Bt,
                                                           unsigned char* __restrict__ Cf8,
                                                           const float* __restrict__ asrc,
                                                           const float* __restrict__ adst,
                                                           float* __restrict__ as_out,
                                                           float* __restrict__ ad_out,
                                                           const int* __restrict__ invp,
                                                           int M, int N, int K,
                                                           int layer1, int aHM, int nbxl) {
    __shared__ ushort As[128 * 64];   // 16 KB
    __shared__ ushort Bs[128 * 64];   // 16 KB
    // XCD-chunked bijective remap (total need not be %8)
    int total = gridDim.x;
    int q8 = total >> 3, r8 = total & 7;
    int xcd = blockIdx.x & 7, within = blockIdx.x >> 3;
    int l = (xcd < r8 ? xcd * (q8 + 1) : r8 * (q8 + 1) + (xcd - r8) * q8) + within;
    int bx = l & ((1 << nbxl) - 1);
    int by = l >> nbxl;

    int t = threadIdx.x;
    int lane = t & 63;
    int wave = t >> 6;
    int wr = (wave >> 1) * 64;        // wave row offset in tile
    int wc = (wave & 1) * 64;         // wave col offset in tile
    int bm = by * 128, bn = bx * 128;
    int q = lane >> 4, l15 = lane & 15;
    size_t kmul = aHM ? (size_t)NP1 : 1;

    const ushort* Aptr[4]; ushort* Alds[4];
    const ushort* Bptr[4]; ushort* Blds[4];
#pragma unroll
    for (int k = 0; k < 4; k++) {
        int c = t + 256 * k;
        int r = c >> 3, kqs = c & 7;
        int kqg = kqs ^ (r & 7);
        int ar = bm + r; if (ar >= M) ar = M - 1;
        Aptr[k] = aHM ? (A + (size_t)ar * 64 + kqg * 8)
                      : (A + (size_t)ar * K + kqg * 8);
        Alds[k] = &As[c * 8];
        Bptr[k] = Bt + (size_t)(bn + r) * K + kqg * 8;   // N % 128 == 0
        Blds[k] = &Bs[c * 8];
    }

    f32x4 acc[4][4];
#pragma unroll
    for (int i = 0; i < 4; i++)
#pragma unroll
        for (int j = 0; j < 4; j++) acc[i][j] = f32x4{0.f, 0.f, 0.f, 0.f};

    for (int k0 = 0; k0 < K; k0 += 64) {
        __syncthreads();   // previous iteration's LDS reads done
        glds16(Aptr[0] + (size_t)k0 * kmul, Alds[0]);
        glds16(Aptr[1] + (size_t)k0 * kmul, Alds[1]);
        glds16(Aptr[2] + (size_t)k0 * kmul, Alds[2]);
        glds16(Aptr[3] + (size_t)k0 * kmul, Alds[3]);
        glds16(Bptr[0] + k0, Blds[0]);
        glds16(Bptr[1] + k0, Blds[1]);
        glds16(Bptr[2] + k0, Blds[2]);
        glds16(Bptr[3] + k0, Blds[3]);
        __syncthreads();   // drains vmcnt (async LDS writes complete)

#pragma unroll
        for (int s = 0; s < 2; s++) {
            int kq = s * 4 + q;
            short8 af[4], bf[4];
#pragma unroll
            for (int i = 0; i < 4; i++) {
                int row = wr + i * 16 + l15;
                int slot = kq ^ (row & 7);
                af[i] = *(const short8*)&As[row * 64 + slot * 8];
            }
#pragma unroll
            for (int j = 0; j < 4; j++) {
                int row = wc + j * 16 + l15;
                int slot = kq ^ (row & 7);
                bf[j] = *(const short8*)&Bs[row * 64 + slot * 8];
            }
#pragma unroll
            for (int i = 0; i < 4; i++)
#pragma unroll
                for (int j = 0; j < 4; j++)
                    acc[i][j] = __builtin_amdgcn_mfma_f32_16x16x32_bf16(af[i], bf[j], acc[i][j], 0, 0, 0);
        }
    }

    // ---- fused attention logits (from fp32 acc) ----
    float av[4], dv[4];
#pragma unroll
    for (int j = 0; j < 4; j++) {
        int cg = bn + wc + j * 16 + l15;
        av[j] = asrc[cg];
        dv[j] = adst[cg];
    }
    float ps[4][4], pd[4][4];
#pragma unroll
    for (int i = 0; i < 4; i++)
#pragma unroll
        for (int r = 0; r < 4; r++) {
            float p = 0.f, d = 0.f;
#pragma unroll
            for (int j = 0; j < 4; j++) {
                p = fmaf(acc[i][j][r], av[j], p);
                d = fmaf(acc[i][j][r], dv[j], d);
            }
            ps[i][r] = p; pd[i][r] = d;
        }
#pragma unroll
    for (int off = 1; off < 16; off <<= 1) {
#pragma unroll
        for (int i = 0; i < 4; i++)
#pragma unroll
            for (int r = 0; r < 4; r++) {
                ps[i][r] += __shfl_xor(ps[i][r], off);
                pd[i][r] += __shfl_xor(pd[i][r], off);
            }
    }

    // ---- C store (fp8) + logit store; C/D layout: col=lane&15, row=q*4+reg
    int hidx = bx * 2 + (wave & 1);   // layer1: wave's 64 cols == one head
#pragma unroll
    for (int i = 0; i < 4; i++) {
#pragma unroll
        for (int r = 0; r < 4; r++) {
            int rg = bm + wr + i * 16 + q * 4 + r;
            if (rg < M) {
                if (layer1) {
                    int rr = invp[rg];   // rank (broadcast: 16 lanes share rg)
#pragma unroll
                    for (int j = 0; j < 4; j++) {
                        int w8 = __builtin_amdgcn_cvt_pk_fp8_f32(acc[i][j][r], acc[i][j][r], 0, false);
                        Cf8[((size_t)hidx * NP1 + rr) * 64 + j * 16 + l15] = (unsigned char)(w8 & 0xff);
                    }
                    if (l15 == 0) {
                        as_out[(size_t)hidx * NP1 + rr] = ps[i][r];   // [head][rank]
                        ad_out[(size_t)hidx * NP1 + rr] = pd[i][r];
                    }
                } else {
#pragma unroll
                    for (int j = 0; j < 4; j++) {
                        int cg = bn + wc + j * 16 + l15;
                        int w8 = __builtin_amdgcn_cvt_pk_fp8_f32(acc[i][j][r], acc[i][j][r], 0, false);
                        Cf8[(size_t)rg * N + cg] = (unsigned char)(w8 & 0xff);
                    }
                    if (l15 == 0) {
                        atomicAdd(&as_out[rg], ps[i][r]);
                        atomicAdd(&ad_out[rg], pd[i][r]);
                    }
                }
            }
        }
    }
}

// ------------- layer-1 aggregation: rank space, head-major, streamed -------
// head = blockIdx % 8 -> XCD k serves only head k; h1f head slice is a
// CONTIGUOUS 1.28MB rank-major array (L2-resident). Nodes are ranks directly;
// consecutive blocks -> consecutive ranks -> h1ab writes are sequential full
// lines. srcs are ushort ranks. Degree-uniform waves via segment sort.
__global__ __launch_bounds__(64) void agg1_kernel(const unsigned char* __restrict__ h1f,
                                                  const float* __restrict__ as1,
                                                  const float* __restrict__ ad1,
                                                  const int* __restrict__ offsets,
                                                  const ushort* __restrict__ srcs,
                                                  const float* __restrict__ b1,
                                                  ushort* __restrict__ h1ab) {
    int b = blockIdx.x;
    int head = b & 7;                 // -> XCD (heuristic)
    int grp = b >> 3;                 // 0..2499
    int lane = threadIdx.x;
    int sub = lane >> 3;              // node slot within wave (0..7)
    int l8 = lane & 7;                // channel-lane (0..7)
    int rk = grp * 8 + sub;           // rank (2500*8 = 20000 exact)
    int cofs = head * 64 + l8 * 8;    // original channel (for b1)
    const unsigned char* hb = h1f + (size_t)head * NP1 * 64 + l8 * 8;
    const float* as1h = as1 + (size_t)head * NP1;
    float adv = ad1[(size_t)head * NP1 + rk];
    int s = offsets[rk], e = offsets[rk + 1];

    float denom = 0.f;
    float acc[8];
#pragma unroll
    for (int k = 0; k < 8; k++) acc[k] = 0.f;

    int i = s;
    uint2 ca = {0u, 0u}, cb = {0u, 0u};
    int csn = N_NODES;
    if (i + 8 <= e) {
        ca = *(const uint2*)&srcs[i];      // 4 ushort ranks
        cb = *(const uint2*)&srcs[i + 4];
        csn = srcs[i + l8];
    }
    while (i + 8 <= e) {
        int sn[8] = {(int)(ca.x & 0xffff), (int)(ca.x >> 16),
                     (int)(ca.y & 0xffff), (int)(ca.y >> 16),
                     (int)(cb.x & 0xffff), (int)(cb.x >> 16),
                     (int)(cb.y & 0xffff), (int)(cb.y >> 16)};
        uint2 r[8];
#pragma unroll
        for (int j = 0; j < 8; j++)
            r[j] = *(const uint2*)&hb[(size_t)sn[j] * 64];
        float aown = as1h[csn];
        int ni = i + 8;
        uint2 na = ca, nb = cb; int nsn = csn;
        if (ni + 8 <= e) {            // preload next batch (overlaps gathers)
            na = *(const uint2*)&srcs[ni];
            nb = *(const uint2*)&srcs[ni + 4];
            nsn = srcs[ni + l8];
        }
        float w_own = __expf(lrelu(aown + adv));
        denom += w_own;
        float ww[8];
#pragma unroll
        for (int j = 0; j < 8; j++) ww[j] = __shfl(w_own, (lane & 56) | j);
#pragma unroll
        for (int j = 0; j < 8; j++) {
            f32x2 pa = __builtin_amdgcn_cvt_pk_f32_fp8(r[j].x, false);
            f32x2 pb = __builtin_amdgcn_cvt_pk_f32_fp8(r[j].x, true);
            f32x2 pc = __builtin_amdgcn_cvt_pk_f32_fp8(r[j].y, false);
            f32x2 pdd = __builtin_amdgcn_cvt_pk_f32_fp8(r[j].y, true);
            acc[0] = fmaf(ww[j], pa.x, acc[0]); acc[1] = fmaf(ww[j], pa.y, acc[1]);
            acc[2] = fmaf(ww[j], pb.x, acc[2]); acc[3] = fmaf(ww[j], pb.y, acc[3]);
            acc[4] = fmaf(ww[j], pc.x, acc[4]); acc[5] = fmaf(ww[j], pc.y, acc[5]);
            acc[6] = fmaf(ww[j], pdd.x, acc[6]); acc[7] = fmaf(ww[j], pdd.y, acc[7]);
        }
        ca = na; cb = nb; csn = nsn; i = ni;
    }
    if (i < e) {   // exactly one 4-edge batch (segments are %4)
        uint2 pa4 = *(const uint2*)&srcs[i];
        int sn[4] = {(int)(pa4.x & 0xffff), (int)(pa4.x >> 16),
                     (int)(pa4.y & 0xffff), (int)(pa4.y >> 16)};
        int snt = srcs[i + (l8 & 3)];
        uint2 r[4];
#pragma unroll
        for (int j = 0; j < 4; j++)
            r[j] = *(const uint2*)&hb[(size_t)sn[j] * 64];
        float w_own = __expf(lrelu(as1h[snt] + adv));
        if (l8 < 4) denom += w_own;
        float ww[4];
#pragma unroll
        for (int j = 0; j < 4; j++) ww[j] = __shfl(w_own, (lane & 56) | j);
#pragma unroll
        for (int j = 0; j < 4; j++) {
            f32x2 pa = __builtin_amdgcn_cvt_pk_f32_fp8(r[j].x, false);
            f32x2 pb = __builtin_amdgcn_cvt_pk_f32_fp8(r[j].x, true);
            f32x2 pc = __builtin_amdgcn_cvt_pk_f32_fp8(r[j].y, false);
            f32x2 pdd = __builtin_amdgcn_cvt_pk_f32_fp8(r[j].y, true);
            acc[0] = fmaf(ww[j], pa.x, acc[0]); acc[1] = fmaf(ww[j], pa.y, acc[1]);
            acc[2] = fmaf(ww[j], pb.x, acc[2]); acc[3] = fmaf(ww[j], pb.y, acc[3]);
            acc[4] = fmaf(ww[j], pc.x, acc[4]); acc[5] = fmaf(ww[j], pc.y, acc[5]);
            acc[6] = fmaf(ww[j], pdd.x, acc[6]); acc[7] = fmaf(ww[j], pdd.y, acc[7]);
        }
    }

    // group-sum denom across the 8 lanes of this node
    denom += __shfl_xor(denom, 1);
    denom += __shfl_xor(denom, 2);
    denom += __shfl_xor(denom, 4);

    float inv = 1.f / (denom + 1e-16f);
    short8 ov;
#pragma unroll
    for (int k = 0; k < 8; k++) {
        float o = acc[k] * inv + b1[cofs + k];
        o = (o > 0.f) ? o : (__expf(o) - 1.f);   // fast ELU (was slow expm1f)
        ov[k] = (short)f2bf(o);
    }
    // head-major rank-major: sequential full-line stream across the grid
    *(short8*)&h1ab[((size_t)head * NP1 + rk) * 64 + l8 * 8] = ov;
}

// Layer 2: rank space; 2 nodes per wave, 32 lanes/node, 8 ch/lane; ushort
// srcs; output scattered to out[perm[rank]] (original order).
__global__ __launch_bounds__(64) void agg2_kernel(const unsigned char* __restrict__ h2f,
                                                  const float* __restrict__ as2,
                                                  const float* __restrict__ ad2,
                                                  const int* __restrict__ offsets,
                                                  const ushort* __restrict__ srcs,
                                                  const int* __restrict__ perm,
                                                  const float* __restrict__ b2,
                                                  float* __restrict__ out) {
    int lane = threadIdx.x;
    int sub = lane >> 5;              // node within wave (0..1)
    int l32 = lane & 31;
    int rk = blockIdx.x * 2 + sub;    // rank (10000*2 = 20000 exact)
    int c8 = l32 * 8;                 // 8 channels of 256
    const unsigned char* hb = h2f + c8;
    float adv = ad2[rk];
    int s = offsets[rk], e = offsets[rk + 1];

    float denom = 0.f;
    float acc[8];
#pragma unroll
    for (int k = 0; k < 8; k++) acc[k] = 0.f;

    int i = s;
    uint2 ca = {0u, 0u}, cb = {0u, 0u};
    int csn = N_NODES;
    if (i + 8 <= e) {
        ca = *(const uint2*)&srcs[i];
        cb = *(const uint2*)&srcs[i + 4];
        csn = srcs[i + (l32 & 7)];
    }
    while (i + 8 <= e) {
        int sn[8] = {(int)(ca.x & 0xffff), (int)(ca.x >> 16),
                     (int)(ca.y & 0xffff), (int)(ca.y >> 16),
                     (int)(cb.x & 0xffff), (int)(cb.x >> 16),
                     (int)(cb.y & 0xffff), (int)(cb.y >> 16)};
        uint2 r[8];
#pragma unroll
        for (int j = 0; j < 8; j++)
            r[j] = *(const uint2*)&hb[(size_t)sn[j] * OUT_CH];
        float aown = as2[csn];
        int ni = i + 8;
        uint2 na = ca, nb = cb; int nsn = csn;
        if (ni + 8 <= e) {
            na = *(const uint2*)&srcs[ni];
            nb = *(const uint2*)&srcs[ni + 4];
            nsn = srcs[ni + (l32 & 7)];
        }
        float w_own = __expf(lrelu(aown + adv));
        if (l32 < 8) denom += w_own;
        float ww[8];
#pragma unroll
        for (int j = 0; j < 8; j++) ww[j] = __shfl(w_own, (lane & 32) | j);
#pragma unroll
        for (int j = 0; j < 8; j++) {
            f32x2 pa = __builtin_amdgcn_cvt_pk_f32_fp8(r[j].x, false);
            f32x2 pb = __builtin_amdgcn_cvt_pk_f32_fp8(r[j].x, true);
            f32x2 pc = __builtin_amdgcn_cvt_pk_f32_fp8(r[j].y, false);
            f32x2 pdd = __builtin_amdgcn_cvt_pk_f32_fp8(r[j].y, true);
            acc[0] = fmaf(ww[j], pa.x, acc[0]); acc[1] = fmaf(ww[j], pa.y, acc[1]);
            acc[2] = fmaf(ww[j], pb.x, acc[2]); acc[3] = fmaf(ww[j], pb.y, acc[3]);
            acc[4] = fmaf(ww[j], pc.x, acc[4]); acc[5] = fmaf(ww[j], pc.y, acc[5]);
            acc[6] = fmaf(ww[j], pdd.x, acc[6]); acc[7] = fmaf(ww[j], pdd.y, acc[7]);
        }
        ca = na; cb = nb; csn = nsn; i = ni;
    }
    if (i < e) {   // one 4-edge batch
        uint2 pa4 = *(const uint2*)&srcs[i];
        int sn[4] = {(int)(pa4.x & 0xffff), (int)(pa4.x >> 16),
                     (int)(pa4.y & 0xffff), (int)(pa4.y >> 16)};
        int snt = srcs[i + (l32 & 3)];
        uint2 r[4];
#pragma unroll
        for (int j = 0; j < 4; j++)
            r[j] = *(const uint2*)&hb[(size_t)sn[j] * OUT_CH];
        float w_own = __expf(lrelu(as2[snt] + adv));
        if (l32 < 4) denom += w_own;
        float ww[4];
#pragma unroll
        for (int j = 0; j < 4; j++) ww[j] = __shfl(w_own, (lane & 32) | j);
#pragma unroll
        for (int j = 0; j < 4; j++) {
            f32x2 pa = __builtin_amdgcn_cvt_pk_f32_fp8(r[j].x, false);
            f32x2 pb = __builtin_amdgcn_cvt_pk_f32_fp8(r[j].x, true);
            f32x2 pc = __builtin_amdgcn_cvt_pk_f32_fp8(r[j].y, false);
            f32x2 pdd = __builtin_amdgcn_cvt_pk_f32_fp8(r[j].y, true);
            acc[0] = fmaf(ww[j], pa.x, acc[0]); acc[1] = fmaf(ww[j], pa.y, acc[1]);
            acc[2] = fmaf(ww[j], pb.x, acc[2]); acc[3] = fmaf(ww[j], pb.y, acc[3]);
            acc[4] = fmaf(ww[j], pc.x, acc[4]); acc[5] = fmaf(ww[j], pc.y, acc[5]);
            acc[6] = fmaf(ww[j], pdd.x, acc[6]); acc[7] = fmaf(ww[j], pdd.y, acc[7]);
        }
    }

    // denom: partial sums live on lanes 0-7 of each 32-group; reduce over 32
    denom += __shfl_xor(denom, 1);
    denom += __shfl_xor(denom, 2);
    denom += __shfl_xor(denom, 4);
    denom += __shfl_xor(denom, 8);
    denom += __shfl_xor(denom, 16);

    float inv = 1.f / (denom + 1e-16f);
    float xv[8];
#pragma unroll
    for (int k = 0; k < 8; k++) xv[k] = acc[k] * inv + b2[c8 + k];

    float mm = xv[0];
#pragma unroll
    for (int k = 1; k < 8; k++) mm = fmaxf(mm, xv[k]);
#pragma unroll
    for (int off = 1; off < 32; off <<= 1) mm = fmaxf(mm, __shfl_xor(mm, off));
    float sum = 0.f;
#pragma unroll
    for (int k = 0; k < 8; k++) sum += __expf(xv[k] - mm);
#pragma unroll
    for (int off = 1; off < 32; off <<= 1) sum += __shfl_xor(sum, off);
    float ls = __logf(sum);
    int vorig = perm[rk];
    float4 o0, o1;
    o0.x = xv[0] - mm - ls; o0.y = xv[1] - mm - ls;
    o0.z = xv[2] - mm - ls; o0.w = xv[3] - mm - ls;
    o1.x = xv[4] - mm - ls; o1.y = xv[5] - mm - ls;
    o1.z = xv[6] - mm - ls; o1.w = xv[7] - mm - ls;
    *(float4*)&out[(size_t)vorig * OUT_CH + c8] = o0;
    *(float4*)&out[(size_t)vorig * OUT_CH + c8 + 4] = o1;
}

static inline size_t align256(size_t x) { return (x + 255) & ~(size_t)255; }

extern "C" void kernel_launch(void* const* d_in, const int* in_sizes, int n_in,
                              void* d_out, int out_size, void* d_ws, size_t ws_size,
                              hipStream_t stream) {
    const float* x    = (const float*)d_in[0];
    const int*   ei   = (const int*)d_in[1];
    const float* W1   = (const float*)d_in[2];
    const float* as1w = (const float*)d_in[3];
    const float* ad1w = (const float*)d_in[4];
    const float* b1   = (const float*)d_in[5];
    const float* W2   = (const float*)d_in[6];
    const float* as2w = (const float*)d_in[7];
    const float* ad2w = (const float*)d_in[8];
    const float* b2   = (const float*)d_in[9];
    float* out = (float*)d_out;

    char* p = (char*)d_ws;
    unsigned char* h1f = (unsigned char*)p; p += align256((size_t)8 * NP1 * 64);       // head-major fp8
    unsigned char* h2f = (unsigned char*)p; p += align256((size_t)NP1 * OUT_CH);       // rank-major fp8
    ushort* xb   = (ushort*)p; p += align256(sizeof(ushort) * (size_t)8 * NP1 * 64);   // covers xb AND h1ab
    ushort* h1ab = xb;   // alias: xb dead after GEMM1, h1ab (head-major bf16) after
    ushort* w1t  = (ushort*)p; p += align256(sizeof(ushort) * (size_t)IN_CH * HID_TOT);
    ushort* w2t  = (ushort*)p; p += align256(sizeof(ushort) * (size_t)HID_TOT * OUT_CH);
    float* as1  = (float*)p; p += align256(sizeof(float) * (size_t)NP1 * 8);
    float* ad1  = (float*)p; p += align256(sizeof(float) * (size_t)NP1 * 8);
    float* as2  = (float*)p; p += align256(sizeof(float) * (size_t)NP1);
    float* ad2  = (float*)p; p += align256(sizeof(float) * (size_t)NP1);
    int* counts  = (int*)p; p += align256(sizeof(int) * (size_t)N_NODES);
    int* offsets = (int*)p; p += align256(sizeof(int) * (size_t)(N_NODES + 1));
    int* cursors = (int*)p; p += align256(sizeof(int) * (size_t)N_NODES);
    int* perm    = (int*)p; p += align256(sizeof(int) * (size_t)N_NODES);
    int* invperm = (int*)p; p += align256(sizeof(int) * (size_t)N_NODES);
    int* pcnt    = (int*)p; p += align256(sizeof(int) * (size_t)N_NODES);
    int* segpre  = (int*)p; p += align256(sizeof(int) * (size_t)NSEG);
    ushort* srcs = (ushort*)p; p += align256(sizeof(ushort) * (size_t)EPAD);

    prep_kernel<<<NA_BLK + NB_BLK + NC_BLK + NZ_BLK, 256, 0, stream>>>(
        x, xb, W1, w1t, W2, w2t, counts, as1, as2, ad2, h1f, h2f);

    // fused CSR build: 1 cooperative kernel replaces hist+perm+scan+scatter
    void* cargs[] = {(void*)&ei, (void*)&counts, (void*)&perm, (void*)&invperm,
                     (void*)&pcnt, (void*)&segpre, (void*)&offsets, (void*)&cursors,
                     (void*)&srcs};
    hipLaunchCooperativeKernel((void*)csr_kernel, dim3(CSR_BLOCKS), dim3(256),
                               cargs, 0, stream);

    // 1D grids with in-kernel XCD-chunked swizzle (nbxl = log2 of col blocks)
    int g1 = (HID_TOT / 128) * ((N_NODES + 127) / 128);   // 4 * 157 = 628
    gemm_mfma_kernel<<<g1, 256, 0, stream>>>(
        xb, w1t, h1f, as1w, ad1w, as1, ad1, invperm, N_NODES, HID_TOT, IN_CH, 1, 0, 2);
    // grid: 2500 rank-groups x 8 head-slices; blockIdx%8 = head -> XCD slice
    agg1_kernel<<<2500 * 8, 64, 0, stream>>>(h1f, as1, ad1, offsets, srcs, b1, h1ab);

    int g2 = (OUT_CH / 128) * ((N_NODES + 127) / 128);    // 2 * 157 = 314
    gemm_mfma_kernel<<<g2, 256, 0, stream>>>(
        h1ab, w2t, h2f, as2w, ad2w, as2, ad2, invperm, N_NODES, OUT_CH, HID_TOT, 0, 1, 1);
    agg2_kernel<<<N_NODES / 2, 64, 0, stream>>>(h2f, as2, ad2, offsets, srcs, perm, b2, out);
}

// Round 13
// 247.996 us; speedup vs baseline: 1.8320x; 1.8320x over previous
//
#include <hip/hip_runtime.h>
#include <math.h>

#define N_NODES 20000
#define NP1     20001   // +1 sentinel slot (rank 20000: zero row, -inf logit)
#define IN_CH   512
#define HID_TOT 512   // 8 heads * 64
#define OUT_CH  256
#define N_EDGE  320000
#define TOT_EDGE (N_EDGE + N_NODES)  // 340000 incl self-loops
#define EPAD    400000               // max padded edges: 340000 + 3*20000
#define NSEG    ((N_NODES + 255) / 256)   // 79 segments of 256 nodes

typedef __attribute__((ext_vector_type(8))) short short8;
typedef __attribute__((ext_vector_type(4))) float f32x4;
typedef __attribute__((ext_vector_type(2))) float f32x2;

__device__ __forceinline__ ushort f2bf(float f) {
    union { float f; unsigned u; } v; v.f = f;
    unsigned u = v.u;
    return (ushort)((u + 0x7fffu + ((u >> 16) & 1u)) >> 16);  // RNE
}

// async global->LDS, 16B per lane (m97 pattern; dest = wave-uniform base + lane*16)
__device__ __forceinline__ void glds16(const ushort* g, ushort* l) {
    __builtin_amdgcn_global_load_lds(
        (const __attribute__((address_space(1))) void*)g,
        (__attribute__((address_space(3))) void*)l, 16, 0, 0);
}

// leaky_relu(a, 0.2) == max(a, 0.2a) for all a (single VALU op)
__device__ __forceinline__ float lrelu(float a) { return fmaxf(a, 0.2f * a); }

// ------- fused prep: cast x, transpose-cast W1/W2, zero/sentinel init ------
#define NA_BLK (N_NODES * IN_CH / 4 / 256)          // 10000
#define NB_BLK ((IN_CH / 64) * (HID_TOT / 4))       // 1024
#define NC_BLK ((HID_TOT / 64) * (OUT_CH / 4))      // 512
#define NZ_BLK ((N_NODES + 255) / 256)              // 79
__global__ __launch_bounds__(256) void prep_kernel(const float* __restrict__ x,
                                                   ushort* __restrict__ xb,
                                                   const float* __restrict__ W1,
                                                   ushort* __restrict__ w1t,
                                                   const float* __restrict__ W2,
                                                   ushort* __restrict__ w2t,
                                                   int* __restrict__ counts,
                                                   float* __restrict__ as1,
                                                   float* __restrict__ as2,
                                                   float* __restrict__ ad2,
                                                   unsigned char* __restrict__ h1f,
                                                   unsigned char* __restrict__ h2f) {
    int b = blockIdx.x;
    int t = threadIdx.x;
    if (b < NA_BLK) {
        int i = b * 256 + t;
        float4 v = *(const float4*)&x[(size_t)i * 4];
        ushort4 o = make_ushort4(f2bf(v.x), f2bf(v.y), f2bf(v.z), f2bf(v.w));
        *(ushort4*)&xb[(size_t)i * 4] = o;
    } else if (b < NA_BLK + NB_BLK) {
        int bb = b - NA_BLK;
        int k = (bb & 7) * 64 + (t & 63);
        int n = (bb >> 3) * 4 + (t >> 6);
        w1t[(size_t)n * IN_CH + k] = f2bf(W1[(size_t)k * HID_TOT + n]);
    } else if (b < NA_BLK + NB_BLK + NC_BLK) {
        int bb = b - NA_BLK - NB_BLK;
        int k = (bb & 7) * 64 + (t & 63);
        int n = (bb >> 3) * 4 + (t >> 6);
        w2t[(size_t)n * HID_TOT + k] = f2bf(W2[(size_t)k * OUT_CH + n]);
    } else {
        int i = (b - NA_BLK - NB_BLK - NC_BLK) * 256 + t;
        if (i < N_NODES) { counts[i] = 0; as2[i] = 0.f; ad2[i] = 0.f; }
        if (i == N_NODES) as2[N_NODES] = -1e30f;            // sentinel logit L2
        if (i < 8) as1[(size_t)i * NP1 + N_NODES] = -1e30f; // sentinel logits L1
        // zero sentinel rows: h1f head-major (8 heads x 64B), h2f (256B)
        if (i < 128)
            ((unsigned*)(h1f + ((size_t)(i >> 4) * NP1 + N_NODES) * 64))[i & 15] = 0u;
        if (i < 64)
            ((unsigned*)(h2f + (size_t)N_NODES * OUT_CH))[i] = 0u;
    }
}

// ---------------- CSR build (counting sort by dst, rank space) -------------
// R12 lesson: a cooperative-kernel fusion of this chain regressed 200us —
// grid.sync() on gfx950 implies cross-XCD L2 visibility (~60us/sync).
// Separate kernel launches ARE the cheap grid barrier. Keep 4 kernels.
__global__ void hist_kernel(const int* __restrict__ ei, int* __restrict__ counts) {
    int e = blockIdx.x * blockDim.x + threadIdx.x;
    if (e >= TOT_EDGE) return;
    int d = (e < N_EDGE) ? ei[N_EDGE + e] : (e - N_EDGE);
    atomicAdd(&counts[d], 1);
}

// segment-local degree sort (256-node segments, fully parallel): perm[rank]=
// node, invperm[node]=rank, pcnt[rank]=degree (rank-ordered, for linear scan).
__global__ __launch_bounds__(256) void perm_kernel(const int* __restrict__ counts,
                                                   int* __restrict__ perm,
                                                   int* __restrict__ invperm,
                                                   int* __restrict__ pcnt) {
    __shared__ int bins[64], starts[64];
    int seg = blockIdx.x;
    int t = threadIdx.x;
    int v = seg * 256 + t;
    bool valid = (v < N_NODES);
    if (t < 64) bins[t] = 0;
    __syncthreads();
    int dreal = 0, d = 0, rank = 0;
    if (valid) {
        dreal = counts[v];
        d = dreal; if (d > 63) d = 63;
        rank = atomicAdd(&bins[d], 1);
    }
    __syncthreads();
    if (t == 0) {
        int r = 0;
        for (int k = 0; k < 64; k++) { starts[k] = r; r += bins[k]; }
    }
    __syncthreads();
    if (valid) {
        int pos = seg * 256 + starts[d] + rank;
        perm[pos] = v;
        invperm[v] = pos;
        pcnt[pos] = dreal;
    }
}

// prefix-sum of padded rank-ordered counts — LINEAR coalesced reads only
__global__ __launch_bounds__(1024) void scan_kernel(const int* __restrict__ pcnt,
                                                    int* __restrict__ offsets,
                                                    int* __restrict__ cursors) {
    const int C = (N_NODES + 1023) / 1024;  // 20
    int t = threadIdx.x;
    int lane = t & 63, wid = t >> 6;
    int base = t * C;
    int cnt[C];
    int sum = 0;
#pragma unroll
    for (int i = 0; i < C; i++) {
        int idx = base + i;
        cnt[i] = (idx < N_NODES) ? pcnt[idx] : 0;
        sum += (cnt[i] + 3) & ~3;   // padded
    }
    int val = sum;
#pragma unroll
    for (int off = 1; off < 64; off <<= 1) {
        int y = __shfl_up(val, off);
        if (lane >= off) val += y;
    }
    __shared__ int wsum[16], woff[16], stotal;
    if (lane == 63) wsum[wid] = val;
    __syncthreads();
    if (t == 0) {
        int r = 0;
        for (int w = 0; w < 16; w++) { woff[w] = r; r += wsum[w]; }
        stotal = r;
    }
    __syncthreads();
    int running = woff[wid] + (val - sum);
#pragma unroll
    for (int i = 0; i < C; i++) {
        int idx = base + i;
        if (idx < N_NODES) {
            offsets[idx] = running;
            cursors[idx] = running;
            running += (cnt[i] + 3) & ~3;   // padded
        }
    }
    if (t == 0) offsets[N_NODES] = stotal;
}

// scatter edges into rank-space CSR (ushort source ranks); grid tail blocks
// fill pad slots with the sentinel rank (disjoint range from cursor writes).
__global__ void scatter_kernel(const int* __restrict__ ei, const int* __restrict__ invperm,
                               const int* __restrict__ pcnt, const int* __restrict__ offsets,
                               int* __restrict__ cursors, ushort* __restrict__ srcs) {
    int idx = blockIdx.x * blockDim.x + threadIdx.x;
    if (idx < TOT_EDGE) {
        int s, d;
        if (idx < N_EDGE) { s = ei[idx]; d = ei[N_EDGE + idx]; } else { s = idx - N_EDGE; d = s; }
        int dr = invperm[d];
        int pos = atomicAdd(&cursors[dr], 1);
        srcs[pos] = (ushort)invperm[s];
    } else {
        int rk = idx - TOT_EDGE;
        if (rk < N_NODES) {
            int o = offsets[rk] + pcnt[rk], e = offsets[rk + 1];
            for (int pp = o; pp < e; pp++) srcs[pp] = (ushort)N_NODES;
        }
    }
}

// --- bf16 MFMA GEMM + fused attention-logit epilogue, fp8 h output --------
// BM=128, BN=128, BK=64. 4 waves in 2x2; wave tile 64x64.
// 1D grid + XCD-chunked bijective swizzle (m204): consecutive chunk entries
// on one XCD share a row-panel -> A panel fetched from HBM once per XCD.
// aHM: A is head-major rank-space [8][NP1][64] bf16 (BK=64 == one head per
//      k-step -> pointer advance is k0*NP1 instead of k0).
// layer1: wave's 64 cols == one head; C (fp8) + logits scattered to
//         invperm[rg] in head-major rank space -> downstream is all linear.
// layer2: C rows are ranks already; 4 atomicAdd logit partials.
__global__ __launch_bounds__(256, 2) void gemm_mfma_kernel(const ushort* __restrict__ A,
                                                           const ushort* __restrict__ Bt,
                                                           unsigned char* __restrict__ Cf8,
                                                           const float* __restrict__ asrc,
                                                           const float* __restrict__ adst,
                                                           float* __restrict__ as_out,
                                                           float* __restrict__ ad_out,
                                                           const int* __restrict__ invp,
                                                           int M, int N, int K,
                                                           int layer1, int aHM, int nbxl) {
    __shared__ ushort As[128 * 64];   // 16 KB
    __shared__ ushort Bs[128 * 64];   // 16 KB
    // XCD-chunked bijective remap (total need not be %8)
    int total = gridDim.x;
    int q8 = total >> 3, r8 = total & 7;
    int xcd = blockIdx.x & 7, within = blockIdx.x >> 3;
    int l = (xcd < r8 ? xcd * (q8 + 1) : r8 * (q8 + 1) + (xcd - r8) * q8) + within;
    int bx = l & ((1 << nbxl) - 1);
    int by = l >> nbxl;

    int t = threadIdx.x;
    int lane = t & 63;
    int wave = t >> 6;
    int wr = (wave >> 1) * 64;        // wave row offset in tile
    int wc = (wave & 1) * 64;         // wave col offset in tile
    int bm = by * 128, bn = bx * 128;
    int q = lane >> 4, l15 = lane & 15;
    size_t kmul = aHM ? (size_t)NP1 : 1;

    const ushort* Aptr[4]; ushort* Alds[4];
    const ushort* Bptr[4]; ushort* Blds[4];
#pragma unroll
    for (int k = 0; k < 4; k++) {
        int c = t + 256 * k;
        int r = c >> 3, kqs = c & 7;
        int kqg = kqs ^ (r & 7);
        int ar = bm + r; if (ar >= M) ar = M - 1;
        Aptr[k] = aHM ? (A + (size_t)ar * 64 + kqg * 8)
                      : (A + (size_t)ar * K + kqg * 8);
        Alds[k] = &As[c * 8];
        Bptr[k] = Bt + (size_t)(bn + r) * K + kqg * 8;   // N % 128 == 0
        Blds[k] = &Bs[c * 8];
    }

    f32x4 acc[4][4];
#pragma unroll
    for (int i = 0; i < 4; i++)
#pragma unroll
        for (int j = 0; j < 4; j++) acc[i][j] = f32x4{0.f, 0.f, 0.f, 0.f};

    for (int k0 = 0; k0 < K; k0 += 64) {
        __syncthreads();   // previous iteration's LDS reads done
        glds16(Aptr[0] + (size_t)k0 * kmul, Alds[0]);
        glds16(Aptr[1] + (size_t)k0 * kmul, Alds[1]);
        glds16(Aptr[2] + (size_t)k0 * kmul, Alds[2]);
        glds16(Aptr[3] + (size_t)k0 * kmul, Alds[3]);
        glds16(Bptr[0] + k0, Blds[0]);
        glds16(Bptr[1] + k0, Blds[1]);
        glds16(Bptr[2] + k0, Blds[2]);
        glds16(Bptr[3] + k0, Blds[3]);
        __syncthreads();   // drains vmcnt (async LDS writes complete)

#pragma unroll
        for (int s = 0; s < 2; s++) {
            int kq = s * 4 + q;
            short8 af[4], bf[4];
#pragma unroll
            for (int i = 0; i < 4; i++) {
                int row = wr + i * 16 + l15;
                int slot = kq ^ (row & 7);
                af[i] = *(const short8*)&As[row * 64 + slot * 8];
            }
#pragma unroll
            for (int j = 0; j < 4; j++) {
                int row = wc + j * 16 + l15;
                int slot = kq ^ (row & 7);
                bf[j] = *(const short8*)&Bs[row * 64 + slot * 8];
            }
#pragma unroll
            for (int i = 0; i < 4; i++)
#pragma unroll
                for (int j = 0; j < 4; j++)
                    acc[i][j] = __builtin_amdgcn_mfma_f32_16x16x32_bf16(af[i], bf[j], acc[i][j], 0, 0, 0);
        }
    }

    // ---- fused attention logits (from fp32 acc) ----
    float av[4], dv[4];
#pragma unroll
    for (int j = 0; j < 4; j++) {
        int cg = bn + wc + j * 16 + l15;
        av[j] = asrc[cg];
        dv[j] = adst[cg];
    }
    float ps[4][4], pd[4][4];
#pragma unroll
    for (int i = 0; i < 4; i++)
#pragma unroll
        for (int r = 0; r < 4; r++) {
            float p = 0.f, d = 0.f;
#pragma unroll
            for (int j = 0; j < 4; j++) {
                p = fmaf(acc[i][j][r], av[j], p);
                d = fmaf(acc[i][j][r], dv[j], d);
            }
            ps[i][r] = p; pd[i][r] = d;
        }
#pragma unroll
    for (int off = 1; off < 16; off <<= 1) {
#pragma unroll
        for (int i = 0; i < 4; i++)
#pragma unroll
            for (int r = 0; r < 4; r++) {
                ps[i][r] += __shfl_xor(ps[i][r], off);
                pd[i][r] += __shfl_xor(pd[i][r], off);
            }
    }

    // ---- C store (fp8) + logit store; C/D layout: col=lane&15, row=q*4+reg
    int hidx = bx * 2 + (wave & 1);   // layer1: wave's 64 cols == one head
#pragma unroll
    for (int i = 0; i < 4; i++) {
#pragma unroll
        for (int r = 0; r < 4; r++) {
            int rg = bm + wr + i * 16 + q * 4 + r;
            if (rg < M) {
                if (layer1) {
                    int rr = invp[rg];   // rank (broadcast: 16 lanes share rg)
#pragma unroll
                    for (int j = 0; j < 4; j++) {
                        int w8 = __builtin_amdgcn_cvt_pk_fp8_f32(acc[i][j][r], acc[i][j][r], 0, false);
                        Cf8[((size_t)hidx * NP1 + rr) * 64 + j * 16 + l15] = (unsigned char)(w8 & 0xff);
                    }
                    if (l15 == 0) {
                        as_out[(size_t)hidx * NP1 + rr] = ps[i][r];   // [head][rank]
                        ad_out[(size_t)hidx * NP1 + rr] = pd[i][r];
                    }
                } else {
#pragma unroll
                    for (int j = 0; j < 4; j++) {
                        int cg = bn + wc + j * 16 + l15;
                        int w8 = __builtin_amdgcn_cvt_pk_fp8_f32(acc[i][j][r], acc[i][j][r], 0, false);
                        Cf8[(size_t)rg * N + cg] = (unsigned char)(w8 & 0xff);
                    }
                    if (l15 == 0) {
                        atomicAdd(&as_out[rg], ps[i][r]);
                        atomicAdd(&ad_out[rg], pd[i][r]);
                    }
                }
            }
        }
    }
}

// ------------- layer-1 aggregation: rank space, head-major, streamed -------
// head = blockIdx % 8 -> XCD k serves only head k; h1f head slice is a
// CONTIGUOUS 1.28MB rank-major array (L2-resident). Nodes are ranks directly;
// consecutive blocks -> consecutive ranks -> h1ab writes are sequential full
// lines. srcs are ushort ranks. Degree-uniform waves via segment sort.
__global__ __launch_bounds__(64) void agg1_kernel(const unsigned char* __restrict__ h1f,
                                                  const float* __restrict__ as1,
                                                  const float* __restrict__ ad1,
                                                  const int* __restrict__ offsets,
                                                  const ushort* __restrict__ srcs,
                                                  const float* __restrict__ b1,
                                                  ushort* __restrict__ h1ab) {
    int b = blockIdx.x;
    int head = b & 7;                 // -> XCD (heuristic)
    int grp = b >> 3;                 // 0..2499
    int lane = threadIdx.x;
    int sub = lane >> 3;              // node slot within wave (0..7)
    int l8 = lane & 7;                // channel-lane (0..7)
    int rk = grp * 8 + sub;           // rank (2500*8 = 20000 exact)
    int cofs = head * 64 + l8 * 8;    // original channel (for b1)
    const unsigned char* hb = h1f + (size_t)head * NP1 * 64 + l8 * 8;
    const float* as1h = as1 + (size_t)head * NP1;
    float adv = ad1[(size_t)head * NP1 + rk];
    int s = offsets[rk], e = offsets[rk + 1];

    float denom = 0.f;
    float acc[8];
#pragma unroll
    for (int k = 0; k < 8; k++) acc[k] = 0.f;

    int i = s;
    uint2 ca = {0u, 0u}, cb = {0u, 0u};
    int csn = N_NODES;
    if (i + 8 <= e) {
        ca = *(const uint2*)&srcs[i];      // 4 ushort ranks
        cb = *(const uint2*)&srcs[i + 4];
        csn = srcs[i + l8];
    }
    while (i + 8 <= e) {
        int sn[8] = {(int)(ca.x & 0xffff), (int)(ca.x >> 16),
                     (int)(ca.y & 0xffff), (int)(ca.y >> 16),
                     (int)(cb.x & 0xffff), (int)(cb.x >> 16),
                     (int)(cb.y & 0xffff), (int)(cb.y >> 16)};
        uint2 r[8];
#pragma unroll
        for (int j = 0; j < 8; j++)
            r[j] = *(const uint2*)&hb[(size_t)sn[j] * 64];
        float aown = as1h[csn];
        int ni = i + 8;
        uint2 na = ca, nb = cb; int nsn = csn;
        if (ni + 8 <= e) {            // preload next batch (overlaps gathers)
            na = *(const uint2*)&srcs[ni];
            nb = *(const uint2*)&srcs[ni + 4];
            nsn = srcs[ni + l8];
        }
        float w_own = __expf(lrelu(aown + adv));
        denom += w_own;
        float ww[8];
#pragma unroll
        for (int j = 0; j < 8; j++) ww[j] = __shfl(w_own, (lane & 56) | j);
#pragma unroll
        for (int j = 0; j < 8; j++) {
            f32x2 pa = __builtin_amdgcn_cvt_pk_f32_fp8(r[j].x, false);
            f32x2 pb = __builtin_amdgcn_cvt_pk_f32_fp8(r[j].x, true);
            f32x2 pc = __builtin_amdgcn_cvt_pk_f32_fp8(r[j].y, false);
            f32x2 pdd = __builtin_amdgcn_cvt_pk_f32_fp8(r[j].y, true);
            acc[0] = fmaf(ww[j], pa.x, acc[0]); acc[1] = fmaf(ww[j], pa.y, acc[1]);
            acc[2] = fmaf(ww[j], pb.x, acc[2]); acc[3] = fmaf(ww[j], pb.y, acc[3]);
            acc[4] = fmaf(ww[j], pc.x, acc[4]); acc[5] = fmaf(ww[j], pc.y, acc[5]);
            acc[6] = fmaf(ww[j], pdd.x, acc[6]); acc[7] = fmaf(ww[j], pdd.y, acc[7]);
        }
        ca = na; cb = nb; csn = nsn; i = ni;
    }
    if (i < e) {   // exactly one 4-edge batch (segments are %4)
        uint2 pa4 = *(const uint2*)&srcs[i];
        int sn[4] = {(int)(pa4.x & 0xffff), (int)(pa4.x >> 16),
                     (int)(pa4.y & 0xffff), (int)(pa4.y >> 16)};
        int snt = srcs[i + (l8 & 3)];
        uint2 r[4];
#pragma unroll
        for (int j = 0; j < 4; j++)
            r[j] = *(const uint2*)&hb[(size_t)sn[j] * 64];
        float w_own = __expf(lrelu(as1h[snt] + adv));
        if (l8 < 4) denom += w_own;
        float ww[4];
#pragma unroll
        for (int j = 0; j < 4; j++) ww[j] = __shfl(w_own, (lane & 56) | j);
#pragma unroll
        for (int j = 0; j < 4; j++) {
            f32x2 pa = __builtin_amdgcn_cvt_pk_f32_fp8(r[j].x, false);
            f32x2 pb = __builtin_amdgcn_cvt_pk_f32_fp8(r[j].x, true);
            f32x2 pc = __builtin_amdgcn_cvt_pk_f32_fp8(r[j].y, false);
            f32x2 pdd = __builtin_amdgcn_cvt_pk_f32_fp8(r[j].y, true);
            acc[0] = fmaf(ww[j], pa.x, acc[0]); acc[1] = fmaf(ww[j], pa.y, acc[1]);
            acc[2] = fmaf(ww[j], pb.x, acc[2]); acc[3] = fmaf(ww[j], pb.y, acc[3]);
            acc[4] = fmaf(ww[j], pc.x, acc[4]); acc[5] = fmaf(ww[j], pc.y, acc[5]);
            acc[6] = fmaf(ww[j], pdd.x, acc[6]); acc[7] = fmaf(ww[j], pdd.y, acc[7]);
        }
    }

    // group-sum denom across the 8 lanes of this node
    denom += __shfl_xor(denom, 1);
    denom += __shfl_xor(denom, 2);
    denom += __shfl_xor(denom, 4);

    float inv = 1.f / (denom + 1e-16f);
    short8 ov;
#pragma unroll
    for (int k = 0; k < 8; k++) {
        float o = acc[k] * inv + b1[cofs + k];
        o = (o > 0.f) ? o : (__expf(o) - 1.f);   // fast ELU (was slow expm1f)
        ov[k] = (short)f2bf(o);
    }
    // head-major rank-major: sequential full-line stream across the grid
    *(short8*)&h1ab[((size_t)head * NP1 + rk) * 64 + l8 * 8] = ov;
}

// Layer 2: rank space; 2 nodes per wave, 32 lanes/node, 8 ch/lane; ushort
// srcs; output scattered to out[perm[rank]] (original order).
__global__ __launch_bounds__(64) void agg2_kernel(const unsigned char* __restrict__ h2f,
                                                  const float* __restrict__ as2,
                                                  const float* __restrict__ ad2,
                                                  const int* __restrict__ offsets,
                                                  const ushort* __restrict__ srcs,
                                                  const int* __restrict__ perm,
                                                  const float* __restrict__ b2,
                                                  float* __restrict__ out) {
    int lane = threadIdx.x;
    int sub = lane >> 5;              // node within wave (0..1)
    int l32 = lane & 31;
    int rk = blockIdx.x * 2 + sub;    // rank (10000*2 = 20000 exact)
    int c8 = l32 * 8;                 // 8 channels of 256
    const unsigned char* hb = h2f + c8;
    float adv = ad2[rk];
    int s = offsets[rk], e = offsets[rk + 1];

    float denom = 0.f;
    float acc[8];
#pragma unroll
    for (int k = 0; k < 8; k++) acc[k] = 0.f;

    int i = s;
    uint2 ca = {0u, 0u}, cb = {0u, 0u};
    int csn = N_NODES;
    if (i + 8 <= e) {
        ca = *(const uint2*)&srcs[i];
        cb = *(const uint2*)&srcs[i + 4];
        csn = srcs[i + (l32 & 7)];
    }
    while (i + 8 <= e) {
        int sn[8] = {(int)(ca.x & 0xffff), (int)(ca.x >> 16),
                     (int)(ca.y & 0xffff), (int)(ca.y >> 16),
                     (int)(cb.x & 0xffff), (int)(cb.x >> 16),
                     (int)(cb.y & 0xffff), (int)(cb.y >> 16)};
        uint2 r[8];
#pragma unroll
        for (int j = 0; j < 8; j++)
            r[j] = *(const uint2*)&hb[(size_t)sn[j] * OUT_CH];
        float aown = as2[csn];
        int ni = i + 8;
        uint2 na = ca, nb = cb; int nsn = csn;
        if (ni + 8 <= e) {
            na = *(const uint2*)&srcs[ni];
            nb = *(const uint2*)&srcs[ni + 4];
            nsn = srcs[ni + (l32 & 7)];
        }
        float w_own = __expf(lrelu(aown + adv));
        if (l32 < 8) denom += w_own;
        float ww[8];
#pragma unroll
        for (int j = 0; j < 8; j++) ww[j] = __shfl(w_own, (lane & 32) | j);
#pragma unroll
        for (int j = 0; j < 8; j++) {
            f32x2 pa = __builtin_amdgcn_cvt_pk_f32_fp8(r[j].x, false);
            f32x2 pb = __builtin_amdgcn_cvt_pk_f32_fp8(r[j].x, true);
            f32x2 pc = __builtin_amdgcn_cvt_pk_f32_fp8(r[j].y, false);
            f32x2 pdd = __builtin_amdgcn_cvt_pk_f32_fp8(r[j].y, true);
            acc[0] = fmaf(ww[j], pa.x, acc[0]); acc[1] = fmaf(ww[j], pa.y, acc[1]);
            acc[2] = fmaf(ww[j], pb.x, acc[2]); acc[3] = fmaf(ww[j], pb.y, acc[3]);
            acc[4] = fmaf(ww[j], pc.x, acc[4]); acc[5] = fmaf(ww[j], pc.y, acc[5]);
            acc[6] = fmaf(ww[j], pdd.x, acc[6]); acc[7] = fmaf(ww[j], pdd.y, acc[7]);
        }
        ca = na; cb = nb; csn = nsn; i = ni;
    }
    if (i < e) {   // one 4-edge batch
        uint2 pa4 = *(const uint2*)&srcs[i];
        int sn[4] = {(int)(pa4.x & 0xffff), (int)(pa4.x >> 16),
                     (int)(pa4.y & 0xffff), (int)(pa4.y >> 16)};
        int snt = srcs[i + (l32 & 3)];
        uint2 r[4];
#pragma unroll
        for (int j = 0; j < 4; j++)
            r[j] = *(const uint2*)&hb[(size_t)sn[j] * OUT_CH];
        float w_own = __expf(lrelu(as2[snt] + adv));
        if (l32 < 4) denom += w_own;
        float ww[4];
#pragma unroll
        for (int j = 0; j < 4; j++) ww[j] = __shfl(w_own, (lane & 32) | j);
#pragma unroll
        for (int j = 0; j < 4; j++) {
            f32x2 pa = __builtin_amdgcn_cvt_pk_f32_fp8(r[j].x, false);
            f32x2 pb = __builtin_amdgcn_cvt_pk_f32_fp8(r[j].x, true);
            f32x2 pc = __builtin_amdgcn_cvt_pk_f32_fp8(r[j].y, false);
            f32x2 pdd = __builtin_amdgcn_cvt_pk_f32_fp8(r[j].y, true);
            acc[0] = fmaf(ww[j], pa.x, acc[0]); acc[1] = fmaf(ww[j], pa.y, acc[1]);
            acc[2] = fmaf(ww[j], pb.x, acc[2]); acc[3] = fmaf(ww[j], pb.y, acc[3]);
            acc[4] = fmaf(ww[j], pc.x, acc[4]); acc[5] = fmaf(ww[j], pc.y, acc[5]);
            acc[6] = fmaf(ww[j], pdd.x, acc[6]); acc[7] = fmaf(ww[j], pdd.y, acc[7]);
        }
    }

    // denom: partial sums live on lanes 0-7 of each 32-group; reduce over 32
    denom += __shfl_xor(denom, 1);
    denom += __shfl_xor(denom, 2);
    denom += __shfl_xor(denom, 4);
    denom += __shfl_xor(denom, 8);
    denom += __shfl_xor(denom, 16);

    float inv = 1.f / (denom + 1e-16f);
    float xv[8];
#pragma unroll
    for (int k = 0; k < 8; k++) xv[k] = acc[k] * inv + b2[c8 + k];

    float mm = xv[0];
#pragma unroll
    for (int k = 1; k < 8; k++) mm = fmaxf(mm, xv[k]);
#pragma unroll
    for (int off = 1; off < 32; off <<= 1) mm = fmaxf(mm, __shfl_xor(mm, off));
    float sum = 0.f;
#pragma unroll
    for (int k = 0; k < 8; k++) sum += __expf(xv[k] - mm);
#pragma unroll
    for (int off = 1; off < 32; off <<= 1) sum += __shfl_xor(sum, off);
    float ls = __logf(sum);
    int vorig = perm[rk];
    float4 o0, o1;
    o0.x = xv[0] - mm - ls; o0.y = xv[1] - mm - ls;
    o0.z = xv[2] - mm - ls; o0.w = xv[3] - mm - ls;
    o1.x = xv[4] - mm - ls; o1.y = xv[5] - mm - ls;
    o1.z = xv[6] - mm - ls; o1.w = xv[7] - mm - ls;
    *(float4*)&out[(size_t)vorig * OUT_CH + c8] = o0;
    *(float4*)&out[(size_t)vorig * OUT_CH + c8 + 4] = o1;
}

static inline size_t align256(size_t x) { return (x + 255) & ~(size_t)255; }

extern "C" void kernel_launch(void* const* d_in, const int* in_sizes, int n_in,
                              void* d_out, int out_size, void* d_ws, size_t ws_size,
                              hipStream_t stream) {
    const float* x    = (const float*)d_in[0];
    const int*   ei   = (const int*)d_in[1];
    const float* W1   = (const float*)d_in[2];
    const float* as1w = (const float*)d_in[3];
    const float* ad1w = (const float*)d_in[4];
    const float* b1   = (const float*)d_in[5];
    const float* W2   = (const float*)d_in[6];
    const float* as2w = (const float*)d_in[7];
    const float* ad2w = (const float*)d_in[8];
    const float* b2   = (const float*)d_in[9];
    float* out = (float*)d_out;

    char* p = (char*)d_ws;
    unsigned char* h1f = (unsigned char*)p; p += align256((size_t)8 * NP1 * 64);       // head-major fp8
    unsigned char* h2f = (unsigned char*)p; p += align256((size_t)NP1 * OUT_CH);       // rank-major fp8
    ushort* xb   = (ushort*)p; p += align256(sizeof(ushort) * (size_t)8 * NP1 * 64);   // covers xb AND h1ab
    ushort* h1ab = xb;   // alias: xb dead after GEMM1, h1ab (head-major bf16) after
    ushort* w1t  = (ushort*)p; p += align256(sizeof(ushort) * (size_t)IN_CH * HID_TOT);
    ushort* w2t  = (ushort*)p; p += align256(sizeof(ushort) * (size_t)HID_TOT * OUT_CH);
    float* as1  = (float*)p; p += align256(sizeof(float) * (size_t)NP1 * 8);
    float* ad1  = (float*)p; p += align256(sizeof(float) * (size_t)NP1 * 8);
    float* as2  = (float*)p; p += align256(sizeof(float) * (size_t)NP1);
    float* ad2  = (float*)p; p += align256(sizeof(float) * (size_t)NP1);
    int* counts  = (int*)p; p += align256(sizeof(int) * (size_t)N_NODES);
    int* offsets = (int*)p; p += align256(sizeof(int) * (size_t)(N_NODES + 1));
    int* cursors = (int*)p; p += align256(sizeof(int) * (size_t)N_NODES);
    int* perm    = (int*)p; p += align256(sizeof(int) * (size_t)N_NODES);
    int* invperm = (int*)p; p += align256(sizeof(int) * (size_t)N_NODES);
    int* pcnt    = (int*)p; p += align256(sizeof(int) * (size_t)N_NODES);
    ushort* srcs = (ushort*)p; p += align256(sizeof(ushort) * (size_t)EPAD);

    prep_kernel<<<NA_BLK + NB_BLK + NC_BLK + NZ_BLK, 256, 0, stream>>>(
        x, xb, W1, w1t, W2, w2t, counts, as1, as2, ad2, h1f, h2f);

    int eb = (TOT_EDGE + 255) / 256;
    hist_kernel<<<eb, 256, 0, stream>>>(ei, counts);
    perm_kernel<<<NSEG, 256, 0, stream>>>(counts, perm, invperm, pcnt);
    scan_kernel<<<1, 1024, 0, stream>>>(pcnt, offsets, cursors);
    int sb = (TOT_EDGE + N_NODES + 255) / 256;
    scatter_kernel<<<sb, 256, 0, stream>>>(ei, invperm, pcnt, offsets, cursors, srcs);

    // 1D grids with in-kernel XCD-chunked swizzle (nbxl = log2 of col blocks)
    int g1 = (HID_TOT / 128) * ((N_NODES + 127) / 128);   // 4 * 157 = 628
    gemm_mfma_kernel<<<g1, 256, 0, stream>>>(
        xb, w1t, h1f, as1w, ad1w, as1, ad1, invperm, N_NODES, HID_TOT, IN_CH, 1, 0, 2);
    // grid: 2500 rank-groups x 8 head-slices; blockIdx%8 = head -> XCD slice
    agg1_kernel<<<2500 * 8, 64, 0, stream>>>(h1f, as1, ad1, offsets, srcs, b1, h1ab);

    int g2 = (OUT_CH / 128) * ((N_NODES + 127) / 128);    // 2 * 157 = 314
    gemm_mfma_kernel<<<g2, 256, 0, stream>>>(
        h1ab, w2t, h2f, as2w, ad2w, as2, ad2, invperm, N_NODES, OUT_CH, HID_TOT, 0, 1, 1);
    agg2_kernel<<<N_NODES / 2, 64, 0, stream>>>(h2f, as2, ad2, offsets, srcs, perm, b2, out);
}